// Round 5
// baseline (220.266 us; speedup 1.0000x reference)
//
#include <hip/hip_runtime.h>
#include <hip/hip_bf16.h>

// CoarseGraining: y[i,b] = heg[b] * sum_j exp(-beta[j,b] * d2(i,j)) * wrho[j]
// N = M = 8192, NB = 16, WIDTH = 32. Inputs float32, output float32.
// R10 wave-per-i: 183us. R11 2 i's/wave: 155us. R12 j-split x2 (separate
//   blocks): 181us REGRESSION (VGPR hit 64-boundary).
// R13 float2-packed math: 133us (VALUBusy 79%, HBM 0.3%, occ 31% grid-capped).
// R14 FAILED: fast-math folded magic-number range reduction.
// R15 poly exp2 on main pipe: 190us REGRESSION (trans executes ON the VALU,
//   no co-issue). Model: exp ~13cy, pk 2cy, busy = 492cy/iter, 21% idle.
// R16 Morton+skip guards: 258us REGRESSION (guards never fire: every plane
//   has a small-beta basis -> bn_max ~ 0).
// R17 j-split x2 in 512-thread blocks, launch_bounds(512,8): 161us REGRESSION
//   -- 2nd arg acts as WORKGROUPS/CU: 8wg x 8waves = 16 waves/SIMD -> VGPR
//   capped at 32 -> acc[16] spilled (WRITE 72MB, FETCH 15.8MB, VALUBusy 63).
//   TLP question unanswered; structure right, register budget wrong.
// R18: same j-split x2 but 256-thread blocks, launch_bounds(256,8): for 256t
//   the 2nd arg == wg/CU -> 8wg x 4waves = 32 waves/CU = 8/SIMD, VGPR cap 64.
//   R13 body = 60 VGPR -> fits, no spill. 2048 blocks x 4 waves; waves
//   (2t,2t+1) share i-pair 2*blk+t, each does one 4096-j half; LDS combine.
// Prediction: VGPR 60-64, WRITE ~0.5MB, cg_pairs 108-118us if R13's 21% idle
//   was TLP-starvation; flat ~130-135 at occ ~65 -> exp-issue roofline.

#define N_PTS 8192
#define M_PTS 8192
#define NBASIS 16
#define WIDTH 32

typedef float v2f __attribute__((ext_vector_type(2)));

__device__ __forceinline__ float exp2_hw(float x) { return __builtin_amdgcn_exp2f(x); }
__device__ __forceinline__ float log2_hw(float x) { return __builtin_amdgcn_logf(x); }

__device__ __forceinline__ float fast_tanh(float z) {
    float a = fabsf(z);
    float t = __expf(-2.0f * a);
    float r = (1.0f - t) / (1.0f + t);
    return copysignf(r, z);
}

__device__ __forceinline__ float log_cosh_f(float x) {
    float a = fabsf(x);
    return a + __logf(1.0f + __expf(-2.0f * a)) - 0.6931471805599453f;
}

// ---------------- Stage 1: per-source-point quantities ----------------
// cw[j]        = (cx, cy, cz, wrho)
// bnq[q*N + j] = float4{ bn[j][4q..4q+3] }, bn = -log2(e)*beta (q-plane layout)
// hegf[0..15]  = log_cosh(embed(0))^1.5
__global__ __launch_bounds__(64)
void cg_prep(const float* __restrict__ rho,
             const float* __restrict__ gamma,
             const float* __restrict__ coords,
             const float* __restrict__ weights,
             const float* __restrict__ w1,
             const float* __restrict__ b1,
             const float* __restrict__ w2,
             const float* __restrict__ b2,
             float4* __restrict__ cw,
             float4* __restrict__ bnq,
             float* __restrict__ hegf)
{
    const float PI_F = 3.14159265358979323846f;
    const float LOG2E = 1.4426950408889634f;

    __shared__ float s_w1[WIDTH], s_b1[WIDTH], s_w2[WIDTH * NBASIS], s_b2[NBASIS];
    int t = threadIdx.x;
    if (t < WIDTH) { s_w1[t] = w1[t]; s_b1[t] = b1[t]; }
    if (t < NBASIS) s_b2[t] = b2[t];
    #pragma unroll
    for (int k = 0; k < 8; ++k) s_w2[t + 64 * k] = w2[t + 64 * k];
    __syncthreads();

    int j = blockIdx.x * 64 + t;
    {
        float r = rho[j];
        float g = gamma[j];
        const float c83 = 38.28312007948569f;              // 4*(3*pi^2)^(2/3)
        float r83 = exp2_hw(2.6666666667f * log2_hw(r));   // r^(8/3)
        float s2 = g / (c83 * r83);
        float x = __logf(s2 + 1e-4f);

        float emb[NBASIS];
        #pragma unroll
        for (int b = 0; b < NBASIS; ++b) emb[b] = s_b2[b];
        #pragma unroll 4
        for (int w = 0; w < WIDTH; ++w) {
            float h = fast_tanh(fmaf(x, s_w1[w], s_b1[w]));
            #pragma unroll
            for (int b = 0; b < NBASIS; ++b)
                emb[b] = fmaf(h, s_w2[w * NBASIS + b], emb[b]);
        }
        float pref = PI_F * exp2_hw(0.6666666667f * log2_hw(0.5f * r));
        float scale = -LOG2E * pref;
        #pragma unroll
        for (int q = 0; q < 4; ++q) {
            bnq[q * N_PTS + j] = make_float4(scale * log_cosh_f(emb[4 * q + 0]),
                                             scale * log_cosh_f(emb[4 * q + 1]),
                                             scale * log_cosh_f(emb[4 * q + 2]),
                                             scale * log_cosh_f(emb[4 * q + 3]));
        }

        cw[j] = make_float4(coords[j * 3 + 0],
                            coords[j * 3 + 1],
                            coords[j * 3 + 2],
                            weights[j] * r);
    }

    if (blockIdx.x == 0 && t == 0) {
        float emb0[NBASIS];
        #pragma unroll
        for (int b = 0; b < NBASIS; ++b) emb0[b] = s_b2[b];
        for (int w = 0; w < WIDTH; ++w) {
            float h = fast_tanh(s_b1[w]);   // x = 0
            #pragma unroll
            for (int b = 0; b < NBASIS; ++b)
                emb0[b] = fmaf(h, s_w2[w * NBASIS + b], emb0[b]);
        }
        #pragma unroll
        for (int b = 0; b < NBASIS; ++b) {
            float lc = fmaxf(log_cosh_f(emb0[b]), 0.0f);
            hegf[b] = lc * sqrtf(lc);       // lc^1.5
        }
    }
}

// ---------------- Stage 2: all-pairs, 2 i's/wave, j-split x2 in-block ----
// 2048 blocks x 256 threads (4 waves). Wave pair (2t, 2t+1) shares i-pair
// 2*blk+t; wave 2t does j in [0,4096), wave 2t+1 does [4096,8192).
// launch_bounds(256,8): 8 wg/CU x 4 waves = 32 waves/CU = 8 waves/SIMD,
// VGPR cap 64 (body needs 60 -> no spill). Inner loop = R13 exactly.
__global__ __launch_bounds__(256, 8)
void cg_pairs(const float* __restrict__ oc,
              const float4* __restrict__ cw,
              const float4* __restrict__ bnq,
              const float* __restrict__ hegf,
              float* __restrict__ out)
{
    __shared__ v2f s_acc[2][NBASIS];   // partials from half-1 waves (256 B)

    int wib  = threadIdx.x >> 6;       // wave in block: 0..3
    int t    = wib >> 1;               // i-pair slot: 0..1
    int half = wib & 1;                // j-half
    int lane = threadIdx.x & 63;
    int pair = (blockIdx.x << 1) | t;
    int i0 = pair << 1;
    int i1 = i0 | 1;

    v2f oxv = { oc[i0 * 3 + 0], oc[i1 * 3 + 0] };
    v2f oyv = { oc[i0 * 3 + 1], oc[i1 * 3 + 1] };
    v2f ozv = { oc[i0 * 3 + 2], oc[i1 * 3 + 2] };

    v2f acc[NBASIS];
    #pragma unroll
    for (int b = 0; b < NBASIS; ++b) acc[b] = (v2f)0.0f;

    int jbase = half << 12;            // 0 or 4096

    #pragma unroll 2
    for (int k = 0; k < N_PTS / 128; ++k) {      // 64 iters per wave
        int j = jbase + (k << 6) + lane;         // lane-consecutive: coalesced
        float4 c = cw[j];
        v2f dx = oxv - c.x;                      // pk_add (scalar broadcast)
        v2f dy = oyv - c.y;
        v2f dz = ozv - c.z;
        v2f d2 = dx * dx + dy * dy + dz * dz;    // pk_mul + 2x pk_fma
        #pragma unroll
        for (int q = 0; q < 4; ++q) {
            float4 b4 = bnq[q * N_PTS + j];      // coalesced dwordx4
            v2f p0 = b4.x * d2;                  // pk_mul
            v2f p1 = b4.y * d2;
            v2f p2 = b4.z * d2;
            v2f p3 = b4.w * d2;
            v2f e0 = { exp2_hw(p0.x), exp2_hw(p0.y) };
            v2f e1 = { exp2_hw(p1.x), exp2_hw(p1.y) };
            v2f e2 = { exp2_hw(p2.x), exp2_hw(p2.y) };
            v2f e3 = { exp2_hw(p3.x), exp2_hw(p3.y) };
            acc[q * 4 + 0] += e0 * c.w;          // pk_fma
            acc[q * 4 + 1] += e1 * c.w;
            acc[q * 4 + 2] += e2 * c.w;
            acc[q * 4 + 3] += e3 * c.w;
        }
    }

    // 6-step butterfly all-reduce over 64 lanes, 16 v2f values
    #pragma unroll
    for (int m = 1; m < 64; m <<= 1) {
        #pragma unroll
        for (int b = 0; b < NBASIS; ++b) {
            v2f other = { __shfl_xor(acc[b].x, m, 64),
                          __shfl_xor(acc[b].y, m, 64) };
            acc[b] += other;
        }
    }

    // combine the two j-halves via LDS, then store with hegf fused
    if (half == 1 && lane < NBASIS) s_acc[t][lane] = acc[lane];
    __syncthreads();
    if (half == 0 && lane < NBASIS) {
        v2f tot = acc[lane] + s_acc[t][lane];
        float h = hegf[lane];
        out[i0 * NBASIS + lane] = tot.x * h;
        out[i1 * NBASIS + lane] = tot.y * h;
    }
}

extern "C" void kernel_launch(void* const* d_in, const int* in_sizes, int n_in,
                              void* d_out, int out_size, void* d_ws, size_t ws_size,
                              hipStream_t stream) {
    const float* rho        = (const float*)d_in[0];
    const float* gamma      = (const float*)d_in[1];
    const float* coords     = (const float*)d_in[2];
    const float* weights    = (const float*)d_in[3];
    const float* out_coords = (const float*)d_in[4];
    const float* w1         = (const float*)d_in[5];
    const float* b1         = (const float*)d_in[6];
    const float* w2         = (const float*)d_in[7];
    const float* b2         = (const float*)d_in[8];

    char* ws = (char*)d_ws;
    // ws layout (640 KiB + 64 B):
    //   cw   : N * float4              = 128 KiB  @ 0
    //   bnq  : 4 planes * N * float4   = 512 KiB  @ 128K
    //   hegf : 16 * float                          @ 640K
    float4* cw   = (float4*)(ws);
    float4* bnq  = (float4*)(ws + (128 << 10));
    float*  hegf = (float*) (ws + (640 << 10));

    cg_prep<<<N_PTS / 64, 64, 0, stream>>>(rho, gamma, coords, weights,
                                           w1, b1, w2, b2,
                                           cw, bnq, hegf);

    cg_pairs<<<M_PTS / 4, 256, 0, stream>>>(out_coords, cw, bnq, hegf,
                                            (float*)d_out);
}

// Round 6
// 192.109 us; speedup vs baseline: 1.1466x; 1.1466x over previous
//
#include <hip/hip_runtime.h>
#include <hip/hip_bf16.h>

// CoarseGraining: y[i,b] = heg[b] * sum_j exp(-beta[j,b] * d2(i,j)) * wrho[j]
// N = M = 8192, NB = 16, WIDTH = 32. Inputs float32, output float32.
// R10 wave-per-i: 183us. R11 2 i's/wave: 155us. R12 j-split x2 (separate
//   blocks): 181us REGRESSION (VGPR 64-boundary).
// R13 float2-packed math: 133us (VALUBusy 79%, HBM 0.3%, occ 31% grid-capped).
// R14 FAILED: fast-math folded magic-number range reduction.
// R15 poly exp2 on main pipe: 190us REGRESSION (trans executes ON the VALU).
//   Model: exp ~13cy, pk 2cy, busy = 32*13 + 38*2 = 492cy/iter, 21% idle.
// R16 Morton+skip guards: 258us REGRESSION (guards never fire).
// R17 j-split x2, launch_bounds(512,8): 161us -- VGPR capped 32, spilled.
// R18 j-split x2, launch_bounds(256,8): 163us -- VGPR STILL 32 (spill, WRITE
//   72MB). Empirical rule: VGPR cap ~= 256 / (2nd arg) on this toolchain;
//   asking 8 waves/EU forces cap 32 < acc[16]'s 32 VGPRs -> guaranteed spill.
// R19: same j-split structure, launch_bounds(256,4) (cap 64; R13 body = 60
//   VGPR, proven). Do NOT request occupancy -- hardware grants 8 waves/SIMD
//   automatically at VGPR<=64 (m69). 8192 waves supply the TLP.
// Issue-floor arithmetic: 8192 waves x 64 iter x 492cy / 1024 SIMD / 2.4GHz
//   = 105us at 100% issue. R13 = 133us at 79% busy (4 waves/SIMD).
// Prediction: VGPR 60-64, WRITE ~0.5MB, occ ~60-65%, VALUBusy 88-93%,
//   cg_pairs 108-118us. If flat ~130 with no spill -> exp-issue roofline.

#define N_PTS 8192
#define M_PTS 8192
#define NBASIS 16
#define WIDTH 32

typedef float v2f __attribute__((ext_vector_type(2)));

__device__ __forceinline__ float exp2_hw(float x) { return __builtin_amdgcn_exp2f(x); }
__device__ __forceinline__ float log2_hw(float x) { return __builtin_amdgcn_logf(x); }

__device__ __forceinline__ float fast_tanh(float z) {
    float a = fabsf(z);
    float t = __expf(-2.0f * a);
    float r = (1.0f - t) / (1.0f + t);
    return copysignf(r, z);
}

__device__ __forceinline__ float log_cosh_f(float x) {
    float a = fabsf(x);
    return a + __logf(1.0f + __expf(-2.0f * a)) - 0.6931471805599453f;
}

// ---------------- Stage 1: per-source-point quantities ----------------
// cw[j]        = (cx, cy, cz, wrho)
// bnq[q*N + j] = float4{ bn[j][4q..4q+3] }, bn = -log2(e)*beta (q-plane layout)
// hegf[0..15]  = log_cosh(embed(0))^1.5
__global__ __launch_bounds__(64)
void cg_prep(const float* __restrict__ rho,
             const float* __restrict__ gamma,
             const float* __restrict__ coords,
             const float* __restrict__ weights,
             const float* __restrict__ w1,
             const float* __restrict__ b1,
             const float* __restrict__ w2,
             const float* __restrict__ b2,
             float4* __restrict__ cw,
             float4* __restrict__ bnq,
             float* __restrict__ hegf)
{
    const float PI_F = 3.14159265358979323846f;
    const float LOG2E = 1.4426950408889634f;

    __shared__ float s_w1[WIDTH], s_b1[WIDTH], s_w2[WIDTH * NBASIS], s_b2[NBASIS];
    int t = threadIdx.x;
    if (t < WIDTH) { s_w1[t] = w1[t]; s_b1[t] = b1[t]; }
    if (t < NBASIS) s_b2[t] = b2[t];
    #pragma unroll
    for (int k = 0; k < 8; ++k) s_w2[t + 64 * k] = w2[t + 64 * k];
    __syncthreads();

    int j = blockIdx.x * 64 + t;
    {
        float r = rho[j];
        float g = gamma[j];
        const float c83 = 38.28312007948569f;              // 4*(3*pi^2)^(2/3)
        float r83 = exp2_hw(2.6666666667f * log2_hw(r));   // r^(8/3)
        float s2 = g / (c83 * r83);
        float x = __logf(s2 + 1e-4f);

        float emb[NBASIS];
        #pragma unroll
        for (int b = 0; b < NBASIS; ++b) emb[b] = s_b2[b];
        #pragma unroll 4
        for (int w = 0; w < WIDTH; ++w) {
            float h = fast_tanh(fmaf(x, s_w1[w], s_b1[w]));
            #pragma unroll
            for (int b = 0; b < NBASIS; ++b)
                emb[b] = fmaf(h, s_w2[w * NBASIS + b], emb[b]);
        }
        float pref = PI_F * exp2_hw(0.6666666667f * log2_hw(0.5f * r));
        float scale = -LOG2E * pref;
        #pragma unroll
        for (int q = 0; q < 4; ++q) {
            bnq[q * N_PTS + j] = make_float4(scale * log_cosh_f(emb[4 * q + 0]),
                                             scale * log_cosh_f(emb[4 * q + 1]),
                                             scale * log_cosh_f(emb[4 * q + 2]),
                                             scale * log_cosh_f(emb[4 * q + 3]));
        }

        cw[j] = make_float4(coords[j * 3 + 0],
                            coords[j * 3 + 1],
                            coords[j * 3 + 2],
                            weights[j] * r);
    }

    if (blockIdx.x == 0 && t == 0) {
        float emb0[NBASIS];
        #pragma unroll
        for (int b = 0; b < NBASIS; ++b) emb0[b] = s_b2[b];
        for (int w = 0; w < WIDTH; ++w) {
            float h = fast_tanh(s_b1[w]);   // x = 0
            #pragma unroll
            for (int b = 0; b < NBASIS; ++b)
                emb0[b] = fmaf(h, s_w2[w * NBASIS + b], emb0[b]);
        }
        #pragma unroll
        for (int b = 0; b < NBASIS; ++b) {
            float lc = fmaxf(log_cosh_f(emb0[b]), 0.0f);
            hegf[b] = lc * sqrtf(lc);       // lc^1.5
        }
    }
}

// ---------------- Stage 2: all-pairs, 2 i's/wave, j-split x2 in-block ----
// 2048 blocks x 256 threads (4 waves). Wave pair (2t, 2t+1) shares i-pair
// 2*blk+t; wave 2t does j in [0,4096), wave 2t+1 does [4096,8192).
// launch_bounds(256,4): VGPR cap 64, body = ~60, NO spill; hardware packs
// 8 waves/SIMD at VGPR<=64 on its own. Inner loop = R13 exactly.
__global__ __launch_bounds__(256, 4)
void cg_pairs(const float* __restrict__ oc,
              const float4* __restrict__ cw,
              const float4* __restrict__ bnq,
              const float* __restrict__ hegf,
              float* __restrict__ out)
{
    __shared__ v2f s_acc[2][NBASIS];   // partials from half-1 waves (256 B)

    int wib  = threadIdx.x >> 6;       // wave in block: 0..3
    int t    = wib >> 1;               // i-pair slot: 0..1
    int half = wib & 1;                // j-half
    int lane = threadIdx.x & 63;
    int pair = (blockIdx.x << 1) | t;
    int i0 = pair << 1;
    int i1 = i0 | 1;

    v2f oxv = { oc[i0 * 3 + 0], oc[i1 * 3 + 0] };
    v2f oyv = { oc[i0 * 3 + 1], oc[i1 * 3 + 1] };
    v2f ozv = { oc[i0 * 3 + 2], oc[i1 * 3 + 2] };

    v2f acc[NBASIS];
    #pragma unroll
    for (int b = 0; b < NBASIS; ++b) acc[b] = (v2f)0.0f;

    int jbase = half << 12;            // 0 or 4096

    #pragma unroll 2
    for (int k = 0; k < N_PTS / 128; ++k) {      // 64 iters per wave
        int j = jbase + (k << 6) + lane;         // lane-consecutive: coalesced
        float4 c = cw[j];
        v2f dx = oxv - c.x;                      // pk_add (scalar broadcast)
        v2f dy = oyv - c.y;
        v2f dz = ozv - c.z;
        v2f d2 = dx * dx + dy * dy + dz * dz;    // pk_mul + 2x pk_fma
        #pragma unroll
        for (int q = 0; q < 4; ++q) {
            float4 b4 = bnq[q * N_PTS + j];      // coalesced dwordx4
            v2f p0 = b4.x * d2;                  // pk_mul
            v2f p1 = b4.y * d2;
            v2f p2 = b4.z * d2;
            v2f p3 = b4.w * d2;
            v2f e0 = { exp2_hw(p0.x), exp2_hw(p0.y) };
            v2f e1 = { exp2_hw(p1.x), exp2_hw(p1.y) };
            v2f e2 = { exp2_hw(p2.x), exp2_hw(p2.y) };
            v2f e3 = { exp2_hw(p3.x), exp2_hw(p3.y) };
            acc[q * 4 + 0] += e0 * c.w;          // pk_fma
            acc[q * 4 + 1] += e1 * c.w;
            acc[q * 4 + 2] += e2 * c.w;
            acc[q * 4 + 3] += e3 * c.w;
        }
    }

    // 6-step butterfly all-reduce over 64 lanes, 16 v2f values
    #pragma unroll
    for (int m = 1; m < 64; m <<= 1) {
        #pragma unroll
        for (int b = 0; b < NBASIS; ++b) {
            v2f other = { __shfl_xor(acc[b].x, m, 64),
                          __shfl_xor(acc[b].y, m, 64) };
            acc[b] += other;
        }
    }

    // combine the two j-halves via LDS, then store with hegf fused
    if (half == 1 && lane < NBASIS) s_acc[t][lane] = acc[lane];
    __syncthreads();
    if (half == 0 && lane < NBASIS) {
        v2f tot = acc[lane] + s_acc[t][lane];
        float h = hegf[lane];
        out[i0 * NBASIS + lane] = tot.x * h;
        out[i1 * NBASIS + lane] = tot.y * h;
    }
}

extern "C" void kernel_launch(void* const* d_in, const int* in_sizes, int n_in,
                              void* d_out, int out_size, void* d_ws, size_t ws_size,
                              hipStream_t stream) {
    const float* rho        = (const float*)d_in[0];
    const float* gamma      = (const float*)d_in[1];
    const float* coords     = (const float*)d_in[2];
    const float* weights    = (const float*)d_in[3];
    const float* out_coords = (const float*)d_in[4];
    const float* w1         = (const float*)d_in[5];
    const float* b1         = (const float*)d_in[6];
    const float* w2         = (const float*)d_in[7];
    const float* b2         = (const float*)d_in[8];

    char* ws = (char*)d_ws;
    // ws layout (640 KiB + 64 B):
    //   cw   : N * float4              = 128 KiB  @ 0
    //   bnq  : 4 planes * N * float4   = 512 KiB  @ 128K
    //   hegf : 16 * float                          @ 640K
    float4* cw   = (float4*)(ws);
    float4* bnq  = (float4*)(ws + (128 << 10));
    float*  hegf = (float*) (ws + (640 << 10));

    cg_prep<<<N_PTS / 64, 64, 0, stream>>>(rho, gamma, coords, weights,
                                           w1, b1, w2, b2,
                                           cw, bnq, hegf);

    cg_pairs<<<M_PTS / 4, 256, 0, stream>>>(out_coords, cw, bnq, hegf,
                                            (float*)d_out);
}